// Round 13
// baseline (2244.124 us; speedup 1.0000x reference)
//
#include <hip/hip_runtime.h>
#include <hip/hip_bf16.h>

#define SEQ 118
#define YS  136   // Ybuf stride (272 B, 16B-aligned rows)
#define SQS 40    // sQP/sK stride (80 B)
#define SVS 136   // sVt stride

typedef __attribute__((ext_vector_type(8))) short short8;
typedef __attribute__((ext_vector_type(4))) float f32x4;

__device__ __forceinline__ f32x4 mfma16(short8 a, short8 b, f32x4 c){
  return __builtin_amdgcn_mfma_f32_16x16x32_bf16(a, b, c, 0, 0, 0);
}
__device__ __forceinline__ float bfr(float x){
  return __bfloat162float(__float2bfloat16(x));
}
__device__ __forceinline__ float rcpf(float x){ return __builtin_amdgcn_rcpf(x); }
__device__ __forceinline__ float fsilu(float z){   // z*sigmoid(z), rcp+exp2 (1-ulp parts)
  return z * rcpf(1.f + exp2f(-1.442695041f * z));
}
__device__ __forceinline__ float rsum16(float v){
  v += __shfl_xor(v,1); v += __shfl_xor(v,2); v += __shfl_xor(v,4); v += __shfl_xor(v,8);
  return v;
}
__device__ __forceinline__ unsigned pack_bf2(float lo, float hi){
  __hip_bfloat162 h2 = __float22bfloat162_rn(float2{lo, hi});  // packed RNE cvt
  unsigned u; __builtin_memcpy(&u, &h2, 4);   // bit_cast rejected: non-trivial copy
  return u;
}
// bf16 halves of a packed dword -> f32 (exact)
__device__ __forceinline__ float bf_lo(unsigned u){
  unsigned v = u << 16; float f; __builtin_memcpy(&f, &v, 4); return f;
}
__device__ __forceinline__ float bf_hi(unsigned u){
  unsigned v = u & 0xffff0000u; float f; __builtin_memcpy(&f, &v, 4); return f;
}

// Pre-permuted bf16 weights (verified round 7):
//  wq/wk/wv: [h][n][k], n <-> orig col d = 4n + h (input-side to_heads)
//  w2:       [n][k'], k' = h*32 + r, dh = (r>>1)+(r&1)*16, orig k = h*32 + dh
// Plus RoPE table: trig[h*2048 + s*16 + c] = pack_bf2(cos, sin),
// ang = s * 10000^(-(4c+h)/64) — same RNE rounding as the old in-kernel path.
__global__ void prep_kernel(const float* __restrict__ qkv_w,
                            const float* __restrict__ fc2_w,
                            __hip_bfloat16* __restrict__ wbf,
                            unsigned* __restrict__ trig){
  int i = blockIdx.x * 256 + threadIdx.x;   // 65536 weights (+8192 trig if launched)
  if (i < 65536){
    int seg = i >> 14;
    int r   = i & 16383;
    int row = r >> 7;
    int k   = r & 127;
    float v;
    if (seg < 3){
      int h = row >> 5, n = row & 31;
      v = qkv_w[(seg*128 + 4*n + h)*128 + k];
    } else {
      int h = k >> 5, rr = k & 31;
      int dh = (rr >> 1) + (rr & 1)*16;
      v = fc2_w[row*128 + h*32 + dh];
    }
    wbf[i] = __float2bfloat16(v);
  } else {
    int ti = i - 65536;                 // 0..8191: [h][s][c]
    int h  = ti >> 11;
    int s  = (ti >> 4) & 127;
    int cc = ti & 15;
    float invf = exp2f((float)(4*cc + h) * (-0.20762050593045f)); // 10000^(-d/64)
    float ang  = (float)s * invf;
    trig[ti] = pack_bf2(__cosf(ang), __sinf(ang));
  }
}

// Round 23 = round-21 body EXACTLY (proven 2177 us; round-22's ping-pong+b64
// staging REVERTED — it raised LDS bank conflicts 5.1e7->8.4e7 and regressed)
// + s_setprio(1)/(0) around the five MFMA-dense clusters (Q/K, V, QK^T, PV,
// FC2). Mechanism: the block's 8 waves are barrier-synced, but the TWO
// co-resident blocks per CU run at independent phases — when one block is in
// an MFMA cluster while the other stages/softmaxes, priority biases SIMD
// issue toward feeding the matrix pipe (T5 regime: independent phase mix).
// Zero register/LDS/numeric impact — clean A/B vs round 21.
template<bool TABLE>
__global__ void
__attribute__((amdgpu_flat_work_group_size(512, 512), amdgpu_waves_per_eu(4, 4)))
fused_kernel(const float* __restrict__ x,
             const float* __restrict__ fc1_w, const float* __restrict__ fc1_b,
             const float* __restrict__ qkv_b,
             const float* __restrict__ fc2_b, const float* __restrict__ fc3_w,
             const float* __restrict__ fc3_b,
             const float* __restrict__ ln_g,  const float* __restrict__ ln_b,
             const __hip_bfloat16* __restrict__ wbf,
             const unsigned* __restrict__ trig,
             float* __restrict__ out)
{
  __shared__ __align__(16) char smem[64864];
  __hip_bfloat16* Ybuf = (__hip_bfloat16*)(smem);           // 118 x 136  32096
  __hip_bfloat16* sQP  = (__hip_bfloat16*)(smem + 32096);   // 128 x 40   10240
  __hip_bfloat16* sK   = (__hip_bfloat16*)(smem + 42336);   // 128 x 40   10240
  __hip_bfloat16* sVt  = (__hip_bfloat16*)(smem + 52576);   //  32 x 136   8704
  float*          sCb  = (float*)        (smem + 61280);    // 512 f32     2048
  float*          sQb  = (float*)        (smem + 63328);    // 384 f32     1536

  const __hip_bfloat16* wq  = wbf;
  const __hip_bfloat16* wk  = wbf + 16384;
  const __hip_bfloat16* wvw = wbf + 32768;
  const __hip_bfloat16* w2  = wbf + 49152;

  const int b    = blockIdx.x;
  const int tid  = threadIdx.x;
  const int wv   = tid >> 6;        // wave 0..7 -> 16-row strip
  const int lane = tid & 63;
  const int c    = lane & 15;
  const int quad = lane >> 4;
  const int arow = wv*16 + c;       // this lane's M-row for A/ay fragments

  { // sCb: fc2_b(0..127) fc3_w(128..255) ln_g(256..383) ln_b(384..511)
    int i = tid;
    if (i < 512){
      float v;
      if      (i < 128) v = fc2_b[i];
      else if (i < 256) v = fc3_w[i-128];
      else if (i < 384) v = ln_g [i-256];
      else              v = ln_b [i-384];
      sCb[i] = v;
    }
    if (i < 384) sQb[i] = qkv_b[i];
  }
  __syncthreads();

  float o1[4];

  #pragma unroll 1
  for (int p = 0; p < 2; ++p){
    // ---- A fragments for this pass (registers only) ----
    short8 afr[4];
    if (p == 0){
      float xs = (arow < SEQ) ? x[b*SEQ + arow] : 0.f;
      #pragma unroll
      for (int k4 = 0; k4 < 4; k4++){
        int d0 = k4*32 + quad*8;
        short8 fr;
        #pragma unroll
        for (int i = 0; i < 8; i++){
          float z = xs * fc1_w[d0+i] + fc1_b[d0+i];
          float v = fsilu(z);
          if (arow >= SEQ) v = 0.f;             // pad rows exact zero
          fr[i] = (short)__builtin_bit_cast(unsigned short, __float2bfloat16(v));
        }
        afr[k4] = fr;
      }
    } else {
      #pragma unroll
      for (int k4 = 0; k4 < 4; k4++){
        short8 fr = *(const short8*)(Ybuf + arow*YS + k4*32 + quad*8);
        if (arow >= SEQ) fr = (short8){0,0,0,0,0,0,0,0};  // NaN guard for V path
        afr[k4] = fr;
      }
    }

    #pragma unroll 1
    for (int h = 0; h < 4; ++h){
      { // ---- Q & K head GEMMs + RoPE -> sQP / sK (packed pair k-order) ----
        // Q written pre-scaled by KSC = 1/sqrt(32)/ln2: softmax is pure exp2.
        // Trig table loads issued FIRST so L2 latency hides under the MFMAs.
        unsigned tj[4];
        float invf;
        if (TABLE){
          const unsigned* tp = trig + h*2048 + (wv*16 + quad*4)*16 + c;
          tj[0] = tp[0]; tj[1] = tp[16]; tj[2] = tp[32]; tj[3] = tp[48];
        } else {
          invf = exp2f((float)(4*c + h) * (-0.20762050593045f)); // 10000^(-d/64)
        }
        const __hip_bfloat16* wpq = wq + (h*32 + c)*128 + quad*8;
        const __hip_bfloat16* wpk = wk + (h*32 + c)*128 + quad*8;
        f32x4 q0={0,0,0,0}, q1={0,0,0,0}, k0={0,0,0,0}, k1={0,0,0,0};
        __builtin_amdgcn_s_setprio(1);
        #pragma unroll
        for (int k4 = 0; k4 < 4; k4++){
          short8 bq0 = *(const short8*)(wpq + k4*32);
          short8 bq1 = *(const short8*)(wpq + 2048 + k4*32);
          short8 bk0 = *(const short8*)(wpk + k4*32);
          short8 bk1 = *(const short8*)(wpk + 2048 + k4*32);
          q0 = mfma16(afr[k4], bq0, q0);
          q1 = mfma16(afr[k4], bq1, q1);
          k0 = mfma16(afr[k4], bk0, k0);
          k1 = mfma16(afr[k4], bk1, k1);
        }
        __builtin_amdgcn_s_setprio(0);
        const float KSC = 0.25500526963f;   // (1/sqrt(32)) * (1/ln2)
        float bQ0 = sQb[      4*c + h], bQ1 = sQb[ 64 + 4*c + h];
        float bK0 = sQb[128 + 4*c + h], bK1 = sQb[192 + 4*c + h];
        #pragma unroll
        for (int j = 0; j < 4; j++){
          int s = wv*16 + quad*4 + j;
          float cv, sv;
          if (TABLE){
            cv = bf_lo(tj[j]); sv = bf_hi(tj[j]);
          } else {
            float ang = (float)s * invf;
            cv = bfr(__cosf(ang)); sv = bfr(__sinf(ang));
          }
          float cvq = cv*KSC, svq = sv*KSC;
          float xq1 = q0[j] + bQ0, xq2 = q1[j] + bQ1;
          float xk1 = k0[j] + bK0, xk2 = k1[j] + bK1;
          *(unsigned*)(sQP + s*SQS + 2*c) = pack_bf2( xq1*cvq + xq2*svq, -xq1*svq + xq2*cvq);
          *(unsigned*)(sK  + s*SQS + 2*c) = pack_bf2( xk1*cv  + xk2*sv , -xk1*sv  + xk2*cv );
        }
      }
      { // ---- V head GEMM -> transposed sVt[dh][s] ----
        const __hip_bfloat16* wpv = wvw + (h*32 + c)*128 + quad*8;
        f32x4 v0={0,0,0,0}, v1={0,0,0,0};
        __builtin_amdgcn_s_setprio(1);
        #pragma unroll
        for (int k4 = 0; k4 < 4; k4++){
          short8 b0 = *(const short8*)(wpv + k4*32);
          short8 b1 = *(const short8*)(wpv + 2048 + k4*32);
          v0 = mfma16(afr[k4], b0, v0);
          v1 = mfma16(afr[k4], b1, v1);
        }
        __builtin_amdgcn_s_setprio(0);
        float bV0 = sQb[256 + 4*c + h], bV1 = sQb[320 + 4*c + h];
        int s0 = wv*16 + quad*4;
        *(unsigned*)(sVt + (c   )*SVS + s0    ) = pack_bf2(v0[0]+bV0, v0[1]+bV0);
        *(unsigned*)(sVt + (c   )*SVS + s0 + 2) = pack_bf2(v0[2]+bV0, v0[3]+bV0);
        *(unsigned*)(sVt + (c+16)*SVS + s0    ) = pack_bf2(v1[0]+bV1, v1[1]+bV1);
        *(unsigned*)(sVt + (c+16)*SVS + s0 + 2) = pack_bf2(v1[2]+bV1, v1[3]+bV1);
      }
      __syncthreads();   // K/Vt visible to all waves

      // ---- QK^T SWAPPED: lane (c,quad) holds P[qrow=wv*16+c][k=t*16+quad*4+j]
      short8 aq = *(const short8*)(sQP + arow*SQS + quad*8);
      f32x4 sc[8];
      __builtin_amdgcn_s_setprio(1);
      #pragma unroll
      for (int t = 0; t < 8; t++){
        sc[t] = (f32x4){0.f,0.f,0.f,0.f};
        if (t <= wv){
          short8 bk = *(const short8*)(sK + (t*16 + c)*SQS + quad*8);
          f32x4 z = {0,0,0,0};
          sc[t] = mfma16(bk, aq, z);      // swapped: m = k-index, n = q-row
        }
      }
      __builtin_amdgcn_s_setprio(0);
      // ---- softmax per q-row (in-lane over t,j; cross-lane over quads) ----
      // Diagonal mask with STATIC t index (t==wv guard) — dynamic sc[wv] sends
      // the whole array to scratch (round-19 lesson: 1 GB/dispatch).
      float mx = -3.0e38f;
      #pragma unroll
      for (int t = 0; t < 8; t++){
        if (t == wv){
          #pragma unroll
          for (int j = 0; j < 4; j++){
            float v = (quad*4 + j <= c) ? sc[t][j] : -1.0e9f;
            sc[t][j] = v;
            mx = fmaxf(mx, v);
          }
        } else if (t < wv){
          float m01 = fmaxf(sc[t][0], sc[t][1]);
          float m23 = fmaxf(sc[t][2], sc[t][3]);
          mx = fmaxf(mx, fmaxf(m01, m23));
        }
      }
      mx = fmaxf(mx, __shfl_xor(mx, 16));
      mx = fmaxf(mx, __shfl_xor(mx, 32));
      f32x4 sv4 = {0,0,0,0};
      #pragma unroll
      for (int t = 0; t < 8; t++) if (t <= wv){
        #pragma unroll
        for (int j = 0; j < 4; j++){
          float e = exp2f(sc[t][j] - mx);
          sc[t][j] = e; sv4[j] += e;
        }
      }
      float sum = (sv4[0] + sv4[1]) + (sv4[2] + sv4[3]);
      sum += __shfl_xor(sum, 16);
      sum += __shfl_xor(sum, 32);
      float rnl = rcpf(sum);               // rnorm for qrow wv*16+c
      float rn[4];
      #pragma unroll
      for (int j = 0; j < 4; j++) rn[j] = __shfl(rnl, quad*4 + j);

      // ---- pack P NOW: sc (32 f32) dies here, pdw (16 u32) carries into PV ----
      unsigned pdw[16];
      #pragma unroll
      for (int t = 0; t < 8; t++){
        pdw[2*t    ] = pack_bf2(sc[t][0], sc[t][1]);
        pdw[2*t + 1] = pack_bf2(sc[t][2], sc[t][3]);
      }

      // ---- P@V: stage P^T rows to sQP (4 dword writes/quarter), b128 read ----
      f32x4 y0 = {0,0,0,0}, y1 = {0,0,0,0};
      unsigned* prow = (unsigned*)(sQP + arow*SQS);   // own q-row, 20 dwords
      auto pv_quarter = [&](int qt, unsigned e0, unsigned e1,
                                    unsigned o0, unsigned o1){
        int dw = quad*2;
        prow[dw    ] = e0;
        prow[dw + 1] = e1;
        prow[dw + 8] = o0;
        prow[dw + 9] = o1;
        short8 ap  = *(const short8*)(sQP + arow*SQS + quad*8);
        short8 bv0 = *(const short8*)(sVt + (c   )*SVS + qt*32 + quad*8);
        short8 bv1 = *(const short8*)(sVt + (c+16)*SVS + qt*32 + quad*8);
        y0 = mfma16(ap, bv0, y0);
        y1 = mfma16(ap, bv1, y1);
      };
      int qmax = wv >> 1;
      __builtin_amdgcn_s_setprio(1);
      pv_quarter(0, pdw[0],  pdw[1],  pdw[2],  pdw[3]);
      if (qmax >= 1) pv_quarter(1, pdw[4],  pdw[5],  pdw[6],  pdw[7]);
      if (qmax >= 2) pv_quarter(2, pdw[8],  pdw[9],  pdw[10], pdw[11]);
      if (qmax >= 3) pv_quarter(3, pdw[12], pdw[13], pdw[14], pdw[15]);
      __builtin_amdgcn_s_setprio(0);
      #pragma unroll
      for (int j = 0; j < 4; j++){ y0[j] *= rn[j]; y1[j] *= rn[j]; }

      { // ---- Y -> Ybuf at this head's k'-slice (guarded: 118 rows only) ----
        int s0 = wv*16 + quad*4;
        #pragma unroll
        for (int j = 0; j < 4; j++)
          if (s0 + j < SEQ)
            *(unsigned*)(Ybuf + (s0+j)*YS + h*32 + 2*c) = pack_bf2(y0[j], y1[j]);
      }
      __syncthreads();   // all reads of K/Vt done; also fences Ybuf for FC2
    }

    // ================= FC2 (once per pass) + silu + LN / readout ==========
    short8 ay[4];
    #pragma unroll
    for (int k4 = 0; k4 < 4; k4++)
      ay[k4] = *(const short8*)(Ybuf + arow*YS + k4*32 + quad*8);
    f32x4 xx[8];
    f32x4 S1 = {0,0,0,0}, S2 = {0,0,0,0}, S3 = {0,0,0,0};
    #pragma unroll 1
    for (int t = 0; t < 8; t++){
      f32x4 acc = {0,0,0,0};
      __builtin_amdgcn_s_setprio(1);
      #pragma unroll
      for (int k4 = 0; k4 < 4; k4++){
        short8 bw = *(const short8*)(w2 + (t*16 + c)*128 + k4*32 + quad*8);
        acc = mfma16(ay[k4], bw, acc);
      }
      __builtin_amdgcn_s_setprio(0);
      float bias = sCb[t*16 + c];
      float w3   = sCb[128 + t*16 + c];
      #pragma unroll
      for (int j = 0; j < 4; j++){
        float v = fsilu(acc[j] + bias);
        xx[t][j] = v;
        S1[j] += v; S2[j] += v*v; S3[j] += v*w3;
      }
    }
    #pragma unroll
    for (int j = 0; j < 4; j++){
      float s1 = rsum16(S1[j]), s2 = rsum16(S2[j]), s3 = rsum16(S3[j]);
      int s = wv*16 + quad*4 + j;
      if (p == 0){
        float mu  = s1 * (1.f/128.f);
        float var = fmaxf(s2 * (1.f/128.f) - mu*mu, 0.f);
        float rs  = rsqrtf(var + 1e-5f);
        if (s < SEQ){
          #pragma unroll
          for (int t = 0; t < 8; t++){
            int d = t*16 + c;
            Ybuf[s*YS + d] = __float2bfloat16((xx[t][j] - mu)*rs*sCb[256+d] + sCb[384+d]);
          }
        }
        o1[j] = s3;                        // x1 . fc3_w residual readout
      } else {
        if (c == 0 && s < SEQ) out[b*SEQ + s] = o1[j] + s3 + fc3_b[0];
      }
    }
    if (p == 0) __syncthreads();   // fence LN writes before pass-1 afr reads
  }
}

extern "C" void kernel_launch(void* const* d_in, const int* in_sizes, int n_in,
                              void* d_out, int out_size, void* d_ws, size_t ws_size,
                              hipStream_t stream){
  const float* x     = (const float*)d_in[0];
  const float* fc1_w = (const float*)d_in[1];
  const float* fc1_b = (const float*)d_in[2];
  const float* qkv_w = (const float*)d_in[3];
  const float* qkv_b = (const float*)d_in[4];
  const float* fc2_w = (const float*)d_in[5];
  const float* fc2_b = (const float*)d_in[6];
  const float* fc3_w = (const float*)d_in[7];
  const float* fc3_b = (const float*)d_in[8];
  const float* ln_g  = (const float*)d_in[9];
  const float* ln_b  = (const float*)d_in[10];

  __hip_bfloat16* wbf  = (__hip_bfloat16*)d_ws;             // 65536 bf16 = 128 KB
  unsigned*       trig = (unsigned*)((char*)d_ws + 131072); // 8192 u32 = 32 KB
  const bool ut = ws_size >= 131072 + 32768;

  prep_kernel<<<ut ? 288 : 256, 256, 0, stream>>>(qkv_w, fc2_w, wbf, trig);

  const int B = in_sizes[0] / SEQ;               // 8192
  if (ut)
    fused_kernel<true ><<<B, 512, 0, stream>>>(x, fc1_w, fc1_b, qkv_b, fc2_b, fc3_w,
                                               fc3_b, ln_g, ln_b, wbf, trig, (float*)d_out);
  else
    fused_kernel<false><<<B, 512, 0, stream>>>(x, fc1_w, fc1_b, qkv_b, fc2_b, fc3_w,
                                               fc3_b, ln_g, ln_b, wbf, trig, (float*)d_out);
}

// Round 14
// 2202.204 us; speedup vs baseline: 1.0190x; 1.0190x over previous
//
#include <hip/hip_runtime.h>
#include <hip/hip_bf16.h>

#define SEQ 118
#define YS  168   // Ybuf stride: 128 data + 8 pad + 32-half PV tail; 336 B rows
                  // (84 dw ≡ 20 mod 32 — full bank coverage like SQS=40; the
                  // r12 regression was YS=160 → 80 dw ≡ 16 mod 32 → 2 banks)
#define SQS 40    // sQP/sK stride (80 B)
#define SVS 136   // sVt stride

typedef __attribute__((ext_vector_type(8))) short short8;
typedef __attribute__((ext_vector_type(4))) float f32x4;

__device__ __forceinline__ f32x4 mfma16(short8 a, short8 b, f32x4 c){
  return __builtin_amdgcn_mfma_f32_16x16x32_bf16(a, b, c, 0, 0, 0);
}
__device__ __forceinline__ float bfr(float x){
  return __bfloat162float(__float2bfloat16(x));
}
__device__ __forceinline__ float rcpf(float x){ return __builtin_amdgcn_rcpf(x); }
__device__ __forceinline__ float fsilu(float z){   // z*sigmoid(z), rcp+exp2 (1-ulp parts)
  return z * rcpf(1.f + exp2f(-1.442695041f * z));
}
__device__ __forceinline__ float rsum16(float v){
  v += __shfl_xor(v,1); v += __shfl_xor(v,2); v += __shfl_xor(v,4); v += __shfl_xor(v,8);
  return v;
}
__device__ __forceinline__ unsigned pack_bf2(float lo, float hi){
  __hip_bfloat162 h2 = __float22bfloat162_rn(float2{lo, hi});  // packed RNE cvt
  unsigned u; __builtin_memcpy(&u, &h2, 4);   // bit_cast rejected: non-trivial copy
  return u;
}
// bf16 halves of a packed dword -> f32 (exact)
__device__ __forceinline__ float bf_lo(unsigned u){
  unsigned v = u << 16; float f; __builtin_memcpy(&f, &v, 4); return f;
}
__device__ __forceinline__ float bf_hi(unsigned u){
  unsigned v = u & 0xffff0000u; float f; __builtin_memcpy(&f, &v, 4); return f;
}

// Pre-permuted bf16 weights (verified round 7):
//  wq/wk/wv: [h][n][k], n <-> orig col d = 4n + h (input-side to_heads)
//  w2:       [n][k'], k' = h*32 + r, dh = (r>>1)+(r&1)*16, orig k = h*32 + dh
// Plus RoPE table: trig[h*2048 + s*16 + c] = pack_bf2(cos, sin),
// ang = s * 10000^(-(4c+h)/64) — same RNE rounding as the old in-kernel path.
__global__ void prep_kernel(const float* __restrict__ qkv_w,
                            const float* __restrict__ fc2_w,
                            __hip_bfloat16* __restrict__ wbf,
                            unsigned* __restrict__ trig){
  int i = blockIdx.x * 256 + threadIdx.x;   // 65536 weights (+8192 trig if launched)
  if (i < 65536){
    int seg = i >> 14;
    int r   = i & 16383;
    int row = r >> 7;
    int k   = r & 127;
    float v;
    if (seg < 3){
      int h = row >> 5, n = row & 31;
      v = qkv_w[(seg*128 + 4*n + h)*128 + k];
    } else {
      int h = k >> 5, rr = k & 31;
      int dh = (rr >> 1) + (rr & 1)*16;
      v = fc2_w[row*128 + h*32 + dh];
    }
    wbf[i] = __float2bfloat16(v);
  } else {
    int ti = i - 65536;                 // 0..8191: [h][s][c]
    int h  = ti >> 11;
    int s  = (ti >> 4) & 127;
    int cc = ti & 15;
    float invf = exp2f((float)(4*cc + h) * (-0.20762050593045f)); // 10000^(-d/64)
    float ang  = (float)s * invf;
    trig[ti] = pack_bf2(__cosf(ang), __sinf(ang));
  }
}

// Round 24 = round-21 (proven 2177 us; round-23's setprio REVERTED, -67us) with:
//  (a) rnorm folded into the P pack: the swapped layout makes each P-row
//      lane-local, so P = rnd_bf16(e * rnl) — deletes the 4 rn-shfls and the
//      post-PV y-scaling (shorter dependent tail after rsum).
//  (b) PV ping-pong staging, bank-corrected: even quarters -> sQP row, odd ->
//      Ybuf row tail at YS=168 (84 dw ≡ 20 mod 32, full bank coverage; r12's
//      regression was the YS=160 stride ≡ 16 mod 32 -> 2-bank pileup, conflict
//      counter 5.1e7 -> 8.4e7). Dword stores kept (r12's b64 merge was also
//      conflict-worse). Breaks the write->read WAR chain between consecutive
//      PV quarters. LDS 75776, still 2 blocks/CU.
template<bool TABLE>
__global__ void
__attribute__((amdgpu_flat_work_group_size(512, 512), amdgpu_waves_per_eu(4, 4)))
fused_kernel(const float* __restrict__ x,
             const float* __restrict__ fc1_w, const float* __restrict__ fc1_b,
             const float* __restrict__ qkv_b,
             const float* __restrict__ fc2_b, const float* __restrict__ fc3_w,
             const float* __restrict__ fc3_b,
             const float* __restrict__ ln_g,  const float* __restrict__ ln_b,
             const __hip_bfloat16* __restrict__ wbf,
             const unsigned* __restrict__ trig,
             float* __restrict__ out)
{
  __shared__ __align__(16) char smem[75776];
  __hip_bfloat16* Ybuf = (__hip_bfloat16*)(smem);           // 128 x 168  43008
  __hip_bfloat16* sQP  = (__hip_bfloat16*)(smem + 43008);   // 128 x 40   10240
  __hip_bfloat16* sK   = (__hip_bfloat16*)(smem + 53248);   // 128 x 40   10240
  __hip_bfloat16* sVt  = (__hip_bfloat16*)(smem + 63488);   //  32 x 136   8704
  float*          sCb  = (float*)        (smem + 72192);    // 512 f32     2048
  float*          sQb  = (float*)        (smem + 74240);    // 384 f32     1536

  const __hip_bfloat16* wq  = wbf;
  const __hip_bfloat16* wk  = wbf + 16384;
  const __hip_bfloat16* wvw = wbf + 32768;
  const __hip_bfloat16* w2  = wbf + 49152;

  const int b    = blockIdx.x;
  const int tid  = threadIdx.x;
  const int wv   = tid >> 6;        // wave 0..7 -> 16-row strip
  const int lane = tid & 63;
  const int c    = lane & 15;
  const int quad = lane >> 4;
  const int arow = wv*16 + c;       // this lane's M-row for A/ay fragments

  { // sCb: fc2_b(0..127) fc3_w(128..255) ln_g(256..383) ln_b(384..511)
    int i = tid;
    if (i < 512){
      float v;
      if      (i < 128) v = fc2_b[i];
      else if (i < 256) v = fc3_w[i-128];
      else if (i < 384) v = ln_g [i-256];
      else              v = ln_b [i-384];
      sCb[i] = v;
    }
    if (i < 384) sQb[i] = qkv_b[i];
  }
  __syncthreads();

  float o1[4];

  #pragma unroll 1
  for (int p = 0; p < 2; ++p){
    // ---- A fragments for this pass (registers only) ----
    short8 afr[4];
    if (p == 0){
      float xs = (arow < SEQ) ? x[b*SEQ + arow] : 0.f;
      #pragma unroll
      for (int k4 = 0; k4 < 4; k4++){
        int d0 = k4*32 + quad*8;
        short8 fr;
        #pragma unroll
        for (int i = 0; i < 8; i++){
          float z = xs * fc1_w[d0+i] + fc1_b[d0+i];
          float v = fsilu(z);
          if (arow >= SEQ) v = 0.f;             // pad rows exact zero
          fr[i] = (short)__builtin_bit_cast(unsigned short, __float2bfloat16(v));
        }
        afr[k4] = fr;
      }
    } else {
      #pragma unroll
      for (int k4 = 0; k4 < 4; k4++){
        short8 fr = *(const short8*)(Ybuf + arow*YS + k4*32 + quad*8);
        if (arow >= SEQ) fr = (short8){0,0,0,0,0,0,0,0};  // NaN guard for V path
        afr[k4] = fr;
      }
    }

    #pragma unroll 1
    for (int h = 0; h < 4; ++h){
      { // ---- Q & K head GEMMs + RoPE -> sQP / sK (packed pair k-order) ----
        // Q written pre-scaled by KSC = 1/sqrt(32)/ln2: softmax is pure exp2.
        // Trig table loads issued FIRST so L2 latency hides under the MFMAs.
        unsigned tj[4];
        float invf;
        if (TABLE){
          const unsigned* tp = trig + h*2048 + (wv*16 + quad*4)*16 + c;
          tj[0] = tp[0]; tj[1] = tp[16]; tj[2] = tp[32]; tj[3] = tp[48];
        } else {
          invf = exp2f((float)(4*c + h) * (-0.20762050593045f)); // 10000^(-d/64)
        }
        const __hip_bfloat16* wpq = wq + (h*32 + c)*128 + quad*8;
        const __hip_bfloat16* wpk = wk + (h*32 + c)*128 + quad*8;
        f32x4 q0={0,0,0,0}, q1={0,0,0,0}, k0={0,0,0,0}, k1={0,0,0,0};
        #pragma unroll
        for (int k4 = 0; k4 < 4; k4++){
          short8 bq0 = *(const short8*)(wpq + k4*32);
          short8 bq1 = *(const short8*)(wpq + 2048 + k4*32);
          short8 bk0 = *(const short8*)(wpk + k4*32);
          short8 bk1 = *(const short8*)(wpk + 2048 + k4*32);
          q0 = mfma16(afr[k4], bq0, q0);
          q1 = mfma16(afr[k4], bq1, q1);
          k0 = mfma16(afr[k4], bk0, k0);
          k1 = mfma16(afr[k4], bk1, k1);
        }
        const float KSC = 0.25500526963f;   // (1/sqrt(32)) * (1/ln2)
        float bQ0 = sQb[      4*c + h], bQ1 = sQb[ 64 + 4*c + h];
        float bK0 = sQb[128 + 4*c + h], bK1 = sQb[192 + 4*c + h];
        #pragma unroll
        for (int j = 0; j < 4; j++){
          int s = wv*16 + quad*4 + j;
          float cv, sv;
          if (TABLE){
            cv = bf_lo(tj[j]); sv = bf_hi(tj[j]);
          } else {
            float ang = (float)s * invf;
            cv = bfr(__cosf(ang)); sv = bfr(__sinf(ang));
          }
          float cvq = cv*KSC, svq = sv*KSC;
          float xq1 = q0[j] + bQ0, xq2 = q1[j] + bQ1;
          float xk1 = k0[j] + bK0, xk2 = k1[j] + bK1;
          *(unsigned*)(sQP + s*SQS + 2*c) = pack_bf2( xq1*cvq + xq2*svq, -xq1*svq + xq2*cvq);
          *(unsigned*)(sK  + s*SQS + 2*c) = pack_bf2( xk1*cv  + xk2*sv , -xk1*sv  + xk2*cv );
        }
      }
      { // ---- V head GEMM -> transposed sVt[dh][s] ----
        const __hip_bfloat16* wpv = wvw + (h*32 + c)*128 + quad*8;
        f32x4 v0={0,0,0,0}, v1={0,0,0,0};
        #pragma unroll
        for (int k4 = 0; k4 < 4; k4++){
          short8 b0 = *(const short8*)(wpv + k4*32);
          short8 b1 = *(const short8*)(wpv + 2048 + k4*32);
          v0 = mfma16(afr[k4], b0, v0);
          v1 = mfma16(afr[k4], b1, v1);
        }
        float bV0 = sQb[256 + 4*c + h], bV1 = sQb[320 + 4*c + h];
        int s0 = wv*16 + quad*4;
        *(unsigned*)(sVt + (c   )*SVS + s0    ) = pack_bf2(v0[0]+bV0, v0[1]+bV0);
        *(unsigned*)(sVt + (c   )*SVS + s0 + 2) = pack_bf2(v0[2]+bV0, v0[3]+bV0);
        *(unsigned*)(sVt + (c+16)*SVS + s0    ) = pack_bf2(v1[0]+bV1, v1[1]+bV1);
        *(unsigned*)(sVt + (c+16)*SVS + s0 + 2) = pack_bf2(v1[2]+bV1, v1[3]+bV1);
      }
      __syncthreads();   // K/Vt visible to all waves

      // ---- QK^T SWAPPED: lane (c,quad) holds P[qrow=wv*16+c][k=t*16+quad*4+j]
      short8 aq = *(const short8*)(sQP + arow*SQS + quad*8);
      f32x4 sc[8];
      #pragma unroll
      for (int t = 0; t < 8; t++){
        sc[t] = (f32x4){0.f,0.f,0.f,0.f};
        if (t <= wv){
          short8 bk = *(const short8*)(sK + (t*16 + c)*SQS + quad*8);
          f32x4 z = {0,0,0,0};
          sc[t] = mfma16(bk, aq, z);      // swapped: m = k-index, n = q-row
        }
      }
      // ---- softmax per q-row (in-lane over t,j; cross-lane over quads) ----
      // Diagonal mask with STATIC t index (t==wv guard) — dynamic sc[wv] sends
      // the whole array to scratch (round-19 lesson: 1 GB/dispatch).
      float mx = -3.0e38f;
      #pragma unroll
      for (int t = 0; t < 8; t++){
        if (t == wv){
          #pragma unroll
          for (int j = 0; j < 4; j++){
            float v = (quad*4 + j <= c) ? sc[t][j] : -1.0e9f;
            sc[t][j] = v;
            mx = fmaxf(mx, v);
          }
        } else if (t < wv){
          float m01 = fmaxf(sc[t][0], sc[t][1]);
          float m23 = fmaxf(sc[t][2], sc[t][3]);
          mx = fmaxf(mx, fmaxf(m01, m23));
        }
      }
      mx = fmaxf(mx, __shfl_xor(mx, 16));
      mx = fmaxf(mx, __shfl_xor(mx, 32));
      f32x4 sv4 = {0,0,0,0};
      #pragma unroll
      for (int t = 0; t < 8; t++) if (t <= wv){
        #pragma unroll
        for (int j = 0; j < 4; j++){
          float e = exp2f(sc[t][j] - mx);
          sc[t][j] = e; sv4[j] += e;
        }
      }
      float sum = (sv4[0] + sv4[1]) + (sv4[2] + sv4[3]);
      sum += __shfl_xor(sum, 16);
      sum += __shfl_xor(sum, 32);
      float rnl = rcpf(sum);               // rnorm for qrow wv*16+c (lane-local)

      // ---- pack P normalized NOW: sc dies; P-rows are lane-local so rnl
      // folds into the pack (no rn shfls, no post-PV y-scaling) ----
      unsigned pdw[16];
      #pragma unroll
      for (int t = 0; t < 8; t++){
        pdw[2*t    ] = pack_bf2(sc[t][0]*rnl, sc[t][1]*rnl);
        pdw[2*t + 1] = pack_bf2(sc[t][2]*rnl, sc[t][3]*rnl);
      }

      // ---- P@V: ping-pong staging (even q -> sQP row, odd q -> Ybuf tail) ----
      f32x4 y0 = {0,0,0,0}, y1 = {0,0,0,0};
      unsigned* prowE = (unsigned*)(sQP  + arow*SQS);        // 16-dword region
      unsigned* prowO = (unsigned*)(Ybuf + arow*YS + 128);   // 16-dword tail
      const __hip_bfloat16* rdE = sQP  + arow*SQS;
      const __hip_bfloat16* rdO = Ybuf + arow*YS + 128;
      auto pv_quarter = [&](int qt, unsigned e0, unsigned e1,
                                    unsigned o0, unsigned o1, bool odd){
        unsigned* pr = odd ? prowO : prowE;
        const __hip_bfloat16* rd = odd ? rdO : rdE;
        int dw = quad*2;
        pr[dw    ] = e0;
        pr[dw + 1] = e1;
        pr[dw + 8] = o0;
        pr[dw + 9] = o1;
        short8 ap  = *(const short8*)(rd + quad*8);
        short8 bv0 = *(const short8*)(sVt + (c   )*SVS + qt*32 + quad*8);
        short8 bv1 = *(const short8*)(sVt + (c+16)*SVS + qt*32 + quad*8);
        y0 = mfma16(ap, bv0, y0);
        y1 = mfma16(ap, bv1, y1);
      };
      int qmax = wv >> 1;
      pv_quarter(0, pdw[0],  pdw[1],  pdw[2],  pdw[3],  false);
      if (qmax >= 1) pv_quarter(1, pdw[4],  pdw[5],  pdw[6],  pdw[7],  true);
      if (qmax >= 2) pv_quarter(2, pdw[8],  pdw[9],  pdw[10], pdw[11], false);
      if (qmax >= 3) pv_quarter(3, pdw[12], pdw[13], pdw[14], pdw[15], true);

      { // ---- Y -> Ybuf at this head's k'-slice (guarded: 118 rows only) ----
        int s0 = wv*16 + quad*4;
        #pragma unroll
        for (int j = 0; j < 4; j++)
          if (s0 + j < SEQ)
            *(unsigned*)(Ybuf + (s0+j)*YS + h*32 + 2*c) = pack_bf2(y0[j], y1[j]);
      }
      __syncthreads();   // all reads of K/Vt done; also fences Ybuf for FC2
    }

    // ================= FC2 (once per pass) + silu + LN / readout ==========
    short8 ay[4];
    #pragma unroll
    for (int k4 = 0; k4 < 4; k4++)
      ay[k4] = *(const short8*)(Ybuf + arow*YS + k4*32 + quad*8);
    f32x4 xx[8];
    f32x4 S1 = {0,0,0,0}, S2 = {0,0,0,0}, S3 = {0,0,0,0};
    #pragma unroll 1
    for (int t = 0; t < 8; t++){
      f32x4 acc = {0,0,0,0};
      #pragma unroll
      for (int k4 = 0; k4 < 4; k4++){
        short8 bw = *(const short8*)(w2 + (t*16 + c)*128 + k4*32 + quad*8);
        acc = mfma16(ay[k4], bw, acc);
      }
      float bias = sCb[t*16 + c];
      float w3   = sCb[128 + t*16 + c];
      #pragma unroll
      for (int j = 0; j < 4; j++){
        float v = fsilu(acc[j] + bias);
        xx[t][j] = v;
        S1[j] += v; S2[j] += v*v; S3[j] += v*w3;
      }
    }
    #pragma unroll
    for (int j = 0; j < 4; j++){
      float s1 = rsum16(S1[j]), s2 = rsum16(S2[j]), s3 = rsum16(S3[j]);
      int s = wv*16 + quad*4 + j;
      if (p == 0){
        float mu  = s1 * (1.f/128.f);
        float var = fmaxf(s2 * (1.f/128.f) - mu*mu, 0.f);
        float rs  = rsqrtf(var + 1e-5f);
        if (s < SEQ){
          #pragma unroll
          for (int t = 0; t < 8; t++){
            int d = t*16 + c;
            Ybuf[s*YS + d] = __float2bfloat16((xx[t][j] - mu)*rs*sCb[256+d] + sCb[384+d]);
          }
        }
        o1[j] = s3;                        // x1 . fc3_w residual readout
      } else {
        if (c == 0 && s < SEQ) out[b*SEQ + s] = o1[j] + s3 + fc3_b[0];
      }
    }
    if (p == 0) __syncthreads();   // fence LN writes before pass-1 afr reads
  }
}

extern "C" void kernel_launch(void* const* d_in, const int* in_sizes, int n_in,
                              void* d_out, int out_size, void* d_ws, size_t ws_size,
                              hipStream_t stream){
  const float* x     = (const float*)d_in[0];
  const float* fc1_w = (const float*)d_in[1];
  const float* fc1_b = (const float*)d_in[2];
  const float* qkv_w = (const float*)d_in[3];
  const float* qkv_b = (const float*)d_in[4];
  const float* fc2_w = (const float*)d_in[5];
  const float* fc2_b = (const float*)d_in[6];
  const float* fc3_w = (const float*)d_in[7];
  const float* fc3_b = (const float*)d_in[8];
  const float* ln_g  = (const float*)d_in[9];
  const float* ln_b  = (const float*)d_in[10];

  __hip_bfloat16* wbf  = (__hip_bfloat16*)d_ws;             // 65536 bf16 = 128 KB
  unsigned*       trig = (unsigned*)((char*)d_ws + 131072); // 8192 u32 = 32 KB
  const bool ut = ws_size >= 131072 + 32768;

  prep_kernel<<<ut ? 288 : 256, 256, 0, stream>>>(qkv_w, fc2_w, wbf, trig);

  const int B = in_sizes[0] / SEQ;               // 8192
  if (ut)
    fused_kernel<true ><<<B, 512, 0, stream>>>(x, fc1_w, fc1_b, qkv_b, fc2_b, fc3_w,
                                               fc3_b, ln_g, ln_b, wbf, trig, (float*)d_out);
  else
    fused_kernel<false><<<B, 512, 0, stream>>>(x, fc1_w, fc1_b, qkv_b, fc2_b, fc3_w,
                                               fc3_b, ln_g, ln_b, wbf, trig, (float*)d_out);
}

// Round 15
// 2167.972 us; speedup vs baseline: 1.0351x; 1.0158x over previous
//
#include <hip/hip_runtime.h>
#include <hip/hip_bf16.h>

#define SEQ 118
#define YS  136   // Ybuf stride (272 B, 16B-aligned rows)
#define SQS 40    // sQP/sK stride (80 B)
#define SVS 136   // sVt stride

typedef __attribute__((ext_vector_type(8))) short short8;
typedef __attribute__((ext_vector_type(4))) float f32x4;

__device__ __forceinline__ f32x4 mfma16(short8 a, short8 b, f32x4 c){
  return __builtin_amdgcn_mfma_f32_16x16x32_bf16(a, b, c, 0, 0, 0);
}
__device__ __forceinline__ float bfr(float x){
  return __bfloat162float(__float2bfloat16(x));
}
__device__ __forceinline__ float rcpf(float x){ return __builtin_amdgcn_rcpf(x); }
__device__ __forceinline__ float fsilu(float z){   // z*sigmoid(z), rcp+exp2 (1-ulp parts)
  return z * rcpf(1.f + exp2f(-1.442695041f * z));
}
__device__ __forceinline__ float rsum16(float v){
  v += __shfl_xor(v,1); v += __shfl_xor(v,2); v += __shfl_xor(v,4); v += __shfl_xor(v,8);
  return v;
}
__device__ __forceinline__ unsigned pack_bf2(float lo, float hi){
  __hip_bfloat162 h2 = __float22bfloat162_rn(float2{lo, hi});  // packed RNE cvt
  unsigned u; __builtin_memcpy(&u, &h2, 4);   // bit_cast rejected: non-trivial copy
  return u;
}
// bf16 halves of a packed dword -> f32 (exact)
__device__ __forceinline__ float bf_lo(unsigned u){
  unsigned v = u << 16; float f; __builtin_memcpy(&f, &v, 4); return f;
}
__device__ __forceinline__ float bf_hi(unsigned u){
  unsigned v = u & 0xffff0000u; float f; __builtin_memcpy(&f, &v, 4); return f;
}

// Pre-permuted bf16 weights (verified round 7):
//  wq/wk/wv: [h][n][k], n <-> orig col d = 4n + h (input-side to_heads)
//  w2:       [n][k'], k' = h*32 + r, dh = (r>>1)+(r&1)*16, orig k = h*32 + dh
// Plus RoPE table: trig[h*2048 + s*16 + c] = pack_bf2(cos, sin),
// ang = s * 10000^(-(4c+h)/64) — same RNE rounding as the old in-kernel path.
__global__ void prep_kernel(const float* __restrict__ qkv_w,
                            const float* __restrict__ fc2_w,
                            __hip_bfloat16* __restrict__ wbf,
                            unsigned* __restrict__ trig){
  int i = blockIdx.x * 256 + threadIdx.x;   // 65536 weights (+8192 trig if launched)
  if (i < 65536){
    int seg = i >> 14;
    int r   = i & 16383;
    int row = r >> 7;
    int k   = r & 127;
    float v;
    if (seg < 3){
      int h = row >> 5, n = row & 31;
      v = qkv_w[(seg*128 + 4*n + h)*128 + k];
    } else {
      int h = k >> 5, rr = k & 31;
      int dh = (rr >> 1) + (rr & 1)*16;
      v = fc2_w[row*128 + h*32 + dh];
    }
    wbf[i] = __float2bfloat16(v);
  } else {
    int ti = i - 65536;                 // 0..8191: [h][s][c]
    int h  = ti >> 11;
    int s  = (ti >> 4) & 127;
    int cc = ti & 15;
    float invf = exp2f((float)(4*cc + h) * (-0.20762050593045f)); // 10000^(-d/64)
    float ang  = (float)s * invf;
    trig[ti] = pack_bf2(__cosf(ang), __sinf(ang));
  }
}

// Round 25 = round-21 EXACTLY (the session best: 2177 us). Terminal revert.
// Negative-result set around this structure (each a distinct mechanism, all
// within noise-to-negative): r22 ping-pong staging (-43us, bank pileup at
// YS=160), r23 setprio arbitration (-67us, co-resident blocks lack phase
// diversity), r24 bank-corrected ping-pong + rnorm-fold (-25us, extra spill).
// Counter state at 2177: MfmaUtil 6.7% == algorithm FLOPs/time, VALU 30%,
// HBM 1.3%, conflicts ~4% of cycles, 2 blocks/CU (LDS+reg pinned). Remaining
// time is the dependent-chain latency of the 8-barrier phase structure.
template<bool TABLE>
__global__ void
__attribute__((amdgpu_flat_work_group_size(512, 512), amdgpu_waves_per_eu(4, 4)))
fused_kernel(const float* __restrict__ x,
             const float* __restrict__ fc1_w, const float* __restrict__ fc1_b,
             const float* __restrict__ qkv_b,
             const float* __restrict__ fc2_b, const float* __restrict__ fc3_w,
             const float* __restrict__ fc3_b,
             const float* __restrict__ ln_g,  const float* __restrict__ ln_b,
             const __hip_bfloat16* __restrict__ wbf,
             const unsigned* __restrict__ trig,
             float* __restrict__ out)
{
  __shared__ __align__(16) char smem[64864];
  __hip_bfloat16* Ybuf = (__hip_bfloat16*)(smem);           // 118 x 136  32096
  __hip_bfloat16* sQP  = (__hip_bfloat16*)(smem + 32096);   // 128 x 40   10240
  __hip_bfloat16* sK   = (__hip_bfloat16*)(smem + 42336);   // 128 x 40   10240
  __hip_bfloat16* sVt  = (__hip_bfloat16*)(smem + 52576);   //  32 x 136   8704
  float*          sCb  = (float*)        (smem + 61280);    // 512 f32     2048
  float*          sQb  = (float*)        (smem + 63328);    // 384 f32     1536

  const __hip_bfloat16* wq  = wbf;
  const __hip_bfloat16* wk  = wbf + 16384;
  const __hip_bfloat16* wvw = wbf + 32768;
  const __hip_bfloat16* w2  = wbf + 49152;

  const int b    = blockIdx.x;
  const int tid  = threadIdx.x;
  const int wv   = tid >> 6;        // wave 0..7 -> 16-row strip
  const int lane = tid & 63;
  const int c    = lane & 15;
  const int quad = lane >> 4;
  const int arow = wv*16 + c;       // this lane's M-row for A/ay fragments

  { // sCb: fc2_b(0..127) fc3_w(128..255) ln_g(256..383) ln_b(384..511)
    int i = tid;
    if (i < 512){
      float v;
      if      (i < 128) v = fc2_b[i];
      else if (i < 256) v = fc3_w[i-128];
      else if (i < 384) v = ln_g [i-256];
      else              v = ln_b [i-384];
      sCb[i] = v;
    }
    if (i < 384) sQb[i] = qkv_b[i];
  }
  __syncthreads();

  float o1[4];

  #pragma unroll 1
  for (int p = 0; p < 2; ++p){
    // ---- A fragments for this pass (registers only) ----
    short8 afr[4];
    if (p == 0){
      float xs = (arow < SEQ) ? x[b*SEQ + arow] : 0.f;
      #pragma unroll
      for (int k4 = 0; k4 < 4; k4++){
        int d0 = k4*32 + quad*8;
        short8 fr;
        #pragma unroll
        for (int i = 0; i < 8; i++){
          float z = xs * fc1_w[d0+i] + fc1_b[d0+i];
          float v = fsilu(z);
          if (arow >= SEQ) v = 0.f;             // pad rows exact zero
          fr[i] = (short)__builtin_bit_cast(unsigned short, __float2bfloat16(v));
        }
        afr[k4] = fr;
      }
    } else {
      #pragma unroll
      for (int k4 = 0; k4 < 4; k4++){
        short8 fr = *(const short8*)(Ybuf + arow*YS + k4*32 + quad*8);
        if (arow >= SEQ) fr = (short8){0,0,0,0,0,0,0,0};  // NaN guard for V path
        afr[k4] = fr;
      }
    }

    #pragma unroll 1
    for (int h = 0; h < 4; ++h){
      { // ---- Q & K head GEMMs + RoPE -> sQP / sK (packed pair k-order) ----
        // Q written pre-scaled by KSC = 1/sqrt(32)/ln2: softmax is pure exp2.
        // Trig table loads issued FIRST so L2 latency hides under the MFMAs.
        unsigned tj[4];
        float invf;
        if (TABLE){
          const unsigned* tp = trig + h*2048 + (wv*16 + quad*4)*16 + c;
          tj[0] = tp[0]; tj[1] = tp[16]; tj[2] = tp[32]; tj[3] = tp[48];
        } else {
          invf = exp2f((float)(4*c + h) * (-0.20762050593045f)); // 10000^(-d/64)
        }
        const __hip_bfloat16* wpq = wq + (h*32 + c)*128 + quad*8;
        const __hip_bfloat16* wpk = wk + (h*32 + c)*128 + quad*8;
        f32x4 q0={0,0,0,0}, q1={0,0,0,0}, k0={0,0,0,0}, k1={0,0,0,0};
        #pragma unroll
        for (int k4 = 0; k4 < 4; k4++){
          short8 bq0 = *(const short8*)(wpq + k4*32);
          short8 bq1 = *(const short8*)(wpq + 2048 + k4*32);
          short8 bk0 = *(const short8*)(wpk + k4*32);
          short8 bk1 = *(const short8*)(wpk + 2048 + k4*32);
          q0 = mfma16(afr[k4], bq0, q0);
          q1 = mfma16(afr[k4], bq1, q1);
          k0 = mfma16(afr[k4], bk0, k0);
          k1 = mfma16(afr[k4], bk1, k1);
        }
        const float KSC = 0.25500526963f;   // (1/sqrt(32)) * (1/ln2)
        float bQ0 = sQb[      4*c + h], bQ1 = sQb[ 64 + 4*c + h];
        float bK0 = sQb[128 + 4*c + h], bK1 = sQb[192 + 4*c + h];
        #pragma unroll
        for (int j = 0; j < 4; j++){
          int s = wv*16 + quad*4 + j;
          float cv, sv;
          if (TABLE){
            cv = bf_lo(tj[j]); sv = bf_hi(tj[j]);
          } else {
            float ang = (float)s * invf;
            cv = bfr(__cosf(ang)); sv = bfr(__sinf(ang));
          }
          float cvq = cv*KSC, svq = sv*KSC;
          float xq1 = q0[j] + bQ0, xq2 = q1[j] + bQ1;
          float xk1 = k0[j] + bK0, xk2 = k1[j] + bK1;
          *(unsigned*)(sQP + s*SQS + 2*c) = pack_bf2( xq1*cvq + xq2*svq, -xq1*svq + xq2*cvq);
          *(unsigned*)(sK  + s*SQS + 2*c) = pack_bf2( xk1*cv  + xk2*sv , -xk1*sv  + xk2*cv );
        }
      }
      { // ---- V head GEMM -> transposed sVt[dh][s] ----
        const __hip_bfloat16* wpv = wvw + (h*32 + c)*128 + quad*8;
        f32x4 v0={0,0,0,0}, v1={0,0,0,0};
        #pragma unroll
        for (int k4 = 0; k4 < 4; k4++){
          short8 b0 = *(const short8*)(wpv + k4*32);
          short8 b1 = *(const short8*)(wpv + 2048 + k4*32);
          v0 = mfma16(afr[k4], b0, v0);
          v1 = mfma16(afr[k4], b1, v1);
        }
        float bV0 = sQb[256 + 4*c + h], bV1 = sQb[320 + 4*c + h];
        int s0 = wv*16 + quad*4;
        *(unsigned*)(sVt + (c   )*SVS + s0    ) = pack_bf2(v0[0]+bV0, v0[1]+bV0);
        *(unsigned*)(sVt + (c   )*SVS + s0 + 2) = pack_bf2(v0[2]+bV0, v0[3]+bV0);
        *(unsigned*)(sVt + (c+16)*SVS + s0    ) = pack_bf2(v1[0]+bV1, v1[1]+bV1);
        *(unsigned*)(sVt + (c+16)*SVS + s0 + 2) = pack_bf2(v1[2]+bV1, v1[3]+bV1);
      }
      __syncthreads();   // K/Vt visible to all waves

      // ---- QK^T SWAPPED: lane (c,quad) holds P[qrow=wv*16+c][k=t*16+quad*4+j]
      short8 aq = *(const short8*)(sQP + arow*SQS + quad*8);
      f32x4 sc[8];
      #pragma unroll
      for (int t = 0; t < 8; t++){
        sc[t] = (f32x4){0.f,0.f,0.f,0.f};
        if (t <= wv){
          short8 bk = *(const short8*)(sK + (t*16 + c)*SQS + quad*8);
          f32x4 z = {0,0,0,0};
          sc[t] = mfma16(bk, aq, z);      // swapped: m = k-index, n = q-row
        }
      }
      // ---- softmax per q-row (in-lane over t,j; cross-lane over quads) ----
      // Diagonal mask with STATIC t index (t==wv guard) — dynamic sc[wv] sends
      // the whole array to scratch (round-19 lesson: 1 GB/dispatch).
      float mx = -3.0e38f;
      #pragma unroll
      for (int t = 0; t < 8; t++){
        if (t == wv){
          #pragma unroll
          for (int j = 0; j < 4; j++){
            float v = (quad*4 + j <= c) ? sc[t][j] : -1.0e9f;
            sc[t][j] = v;
            mx = fmaxf(mx, v);
          }
        } else if (t < wv){
          float m01 = fmaxf(sc[t][0], sc[t][1]);
          float m23 = fmaxf(sc[t][2], sc[t][3]);
          mx = fmaxf(mx, fmaxf(m01, m23));
        }
      }
      mx = fmaxf(mx, __shfl_xor(mx, 16));
      mx = fmaxf(mx, __shfl_xor(mx, 32));
      f32x4 sv4 = {0,0,0,0};
      #pragma unroll
      for (int t = 0; t < 8; t++) if (t <= wv){
        #pragma unroll
        for (int j = 0; j < 4; j++){
          float e = exp2f(sc[t][j] - mx);
          sc[t][j] = e; sv4[j] += e;
        }
      }
      float sum = (sv4[0] + sv4[1]) + (sv4[2] + sv4[3]);
      sum += __shfl_xor(sum, 16);
      sum += __shfl_xor(sum, 32);
      float rnl = rcpf(sum);               // rnorm for qrow wv*16+c
      float rn[4];
      #pragma unroll
      for (int j = 0; j < 4; j++) rn[j] = __shfl(rnl, quad*4 + j);

      // ---- pack P NOW: sc (32 f32) dies here, pdw (16 u32) carries into PV ----
      unsigned pdw[16];
      #pragma unroll
      for (int t = 0; t < 8; t++){
        pdw[2*t    ] = pack_bf2(sc[t][0], sc[t][1]);
        pdw[2*t + 1] = pack_bf2(sc[t][2], sc[t][3]);
      }

      // ---- P@V: stage P^T rows to sQP (4 dword writes/quarter), b128 read ----
      f32x4 y0 = {0,0,0,0}, y1 = {0,0,0,0};
      unsigned* prow = (unsigned*)(sQP + arow*SQS);   // own q-row, 20 dwords
      auto pv_quarter = [&](int qt, unsigned e0, unsigned e1,
                                    unsigned o0, unsigned o1){
        int dw = quad*2;
        prow[dw    ] = e0;
        prow[dw + 1] = e1;
        prow[dw + 8] = o0;
        prow[dw + 9] = o1;
        short8 ap  = *(const short8*)(sQP + arow*SQS + quad*8);
        short8 bv0 = *(const short8*)(sVt + (c   )*SVS + qt*32 + quad*8);
        short8 bv1 = *(const short8*)(sVt + (c+16)*SVS + qt*32 + quad*8);
        y0 = mfma16(ap, bv0, y0);
        y1 = mfma16(ap, bv1, y1);
      };
      int qmax = wv >> 1;
      pv_quarter(0, pdw[0],  pdw[1],  pdw[2],  pdw[3]);
      if (qmax >= 1) pv_quarter(1, pdw[4],  pdw[5],  pdw[6],  pdw[7]);
      if (qmax >= 2) pv_quarter(2, pdw[8],  pdw[9],  pdw[10], pdw[11]);
      if (qmax >= 3) pv_quarter(3, pdw[12], pdw[13], pdw[14], pdw[15]);
      #pragma unroll
      for (int j = 0; j < 4; j++){ y0[j] *= rn[j]; y1[j] *= rn[j]; }

      { // ---- Y -> Ybuf at this head's k'-slice (guarded: 118 rows only) ----
        int s0 = wv*16 + quad*4;
        #pragma unroll
        for (int j = 0; j < 4; j++)
          if (s0 + j < SEQ)
            *(unsigned*)(Ybuf + (s0+j)*YS + h*32 + 2*c) = pack_bf2(y0[j], y1[j]);
      }
      __syncthreads();   // all reads of K/Vt done; also fences Ybuf for FC2
    }

    // ================= FC2 (once per pass) + silu + LN / readout ==========
    short8 ay[4];
    #pragma unroll
    for (int k4 = 0; k4 < 4; k4++)
      ay[k4] = *(const short8*)(Ybuf + arow*YS + k4*32 + quad*8);
    f32x4 xx[8];
    f32x4 S1 = {0,0,0,0}, S2 = {0,0,0,0}, S3 = {0,0,0,0};
    #pragma unroll 1
    for (int t = 0; t < 8; t++){
      f32x4 acc = {0,0,0,0};
      #pragma unroll
      for (int k4 = 0; k4 < 4; k4++){
        short8 bw = *(const short8*)(w2 + (t*16 + c)*128 + k4*32 + quad*8);
        acc = mfma16(ay[k4], bw, acc);
      }
      float bias = sCb[t*16 + c];
      float w3   = sCb[128 + t*16 + c];
      #pragma unroll
      for (int j = 0; j < 4; j++){
        float v = fsilu(acc[j] + bias);
        xx[t][j] = v;
        S1[j] += v; S2[j] += v*v; S3[j] += v*w3;
      }
    }
    #pragma unroll
    for (int j = 0; j < 4; j++){
      float s1 = rsum16(S1[j]), s2 = rsum16(S2[j]), s3 = rsum16(S3[j]);
      int s = wv*16 + quad*4 + j;
      if (p == 0){
        float mu  = s1 * (1.f/128.f);
        float var = fmaxf(s2 * (1.f/128.f) - mu*mu, 0.f);
        float rs  = rsqrtf(var + 1e-5f);
        if (s < SEQ){
          #pragma unroll
          for (int t = 0; t < 8; t++){
            int d = t*16 + c;
            Ybuf[s*YS + d] = __float2bfloat16((xx[t][j] - mu)*rs*sCb[256+d] + sCb[384+d]);
          }
        }
        o1[j] = s3;                        // x1 . fc3_w residual readout
      } else {
        if (c == 0 && s < SEQ) out[b*SEQ + s] = o1[j] + s3 + fc3_b[0];
      }
    }
    if (p == 0) __syncthreads();   // fence LN writes before pass-1 afr reads
  }
}

extern "C" void kernel_launch(void* const* d_in, const int* in_sizes, int n_in,
                              void* d_out, int out_size, void* d_ws, size_t ws_size,
                              hipStream_t stream){
  const float* x     = (const float*)d_in[0];
  const float* fc1_w = (const float*)d_in[1];
  const float* fc1_b = (const float*)d_in[2];
  const float* qkv_w = (const float*)d_in[3];
  const float* qkv_b = (const float*)d_in[4];
  const float* fc2_w = (const float*)d_in[5];
  const float* fc2_b = (const float*)d_in[6];
  const float* fc3_w = (const float*)d_in[7];
  const float* fc3_b = (const float*)d_in[8];
  const float* ln_g  = (const float*)d_in[9];
  const float* ln_b  = (const float*)d_in[10];

  __hip_bfloat16* wbf  = (__hip_bfloat16*)d_ws;             // 65536 bf16 = 128 KB
  unsigned*       trig = (unsigned*)((char*)d_ws + 131072); // 8192 u32 = 32 KB
  const bool ut = ws_size >= 131072 + 32768;

  prep_kernel<<<ut ? 288 : 256, 256, 0, stream>>>(qkv_w, fc2_w, wbf, trig);

  const int B = in_sizes[0] / SEQ;               // 8192
  if (ut)
    fused_kernel<true ><<<B, 512, 0, stream>>>(x, fc1_w, fc1_b, qkv_b, fc2_b, fc3_w,
                                               fc3_b, ln_g, ln_b, wbf, trig, (float*)d_out);
  else
    fused_kernel<false><<<B, 512, 0, stream>>>(x, fc1_w, fc1_b, qkv_b, fc2_b, fc3_w,
                                               fc3_b, ln_g, ln_b, wbf, trig, (float*)d_out);
}